// Round 2
// baseline (501.150 us; speedup 1.0000x reference)
//
#include <hip/hip_runtime.h>
#include <stdint.h>

#define SEQ 2048
#define DIN 2048
#define NH 16
#define HD 128

typedef __attribute__((ext_vector_type(8))) short bf16x8;
typedef __attribute__((ext_vector_type(4))) float f32x4;

__device__ __forceinline__ unsigned short f2bf(float f) {
    unsigned int u = __float_as_uint(f);
    u += 0x7fff + ((u >> 16) & 1);   // round-to-nearest-even
    return (unsigned short)(u >> 16);
}

__device__ __forceinline__ float bf2f(unsigned short u) {
    return __uint_as_float(((unsigned int)u) << 16);
}

__device__ __forceinline__ void gload_lds16(const void* g, void* l) {
    __builtin_amdgcn_global_load_lds(
        (const __attribute__((address_space(1))) unsigned int*)g,
        (__attribute__((address_space(3))) unsigned int*)l,
        16, 0, 0);
}

// ---------------- cast f32 -> bf16 ----------------
__global__ void cast_f32_bf16(const float* __restrict__ in, unsigned short* __restrict__ out, int n) {
    int i = (blockIdx.x * blockDim.x + threadIdx.x) * 4;
    if (i >= n) return;
    float4 v = *reinterpret_cast<const float4*>(in + i);
    ushort4 o;
    o.x = f2bf(v.x); o.y = f2bf(v.y); o.z = f2bf(v.z); o.w = f2bf(v.w);
    *reinterpret_cast<ushort4*>(out + i) = o;
}

// ---------------- GEMM: C[M][N] = A[M][K] * B[N][K]^T (bf16 in, f32 acc) ----------------
template<int OUT_BF16>
__launch_bounds__(256)
__global__ void gemm_bt(const unsigned short* __restrict__ A,
                        const unsigned short* __restrict__ B,
                        void* __restrict__ Cv, int M, int N, int K) {
    __shared__ __align__(16) unsigned short As[128 * 32];
    __shared__ __align__(16) unsigned short Bs[128 * 32];
    const int t = threadIdx.x;
    const int l = t & 63;
    const int w = t >> 6;
    const int wr = w >> 1, wc = w & 1;
    const int row0 = blockIdx.y * 128, col0 = blockIdx.x * 128;
    const int lr = l & 15, lk = (l >> 4) * 8;

    f32x4 acc[4][4] = {};

    const unsigned short* Ag0 = A + (size_t)(row0 + t / 4) * K + (t % 4) * 8;
    const unsigned short* Ag1 = Ag0 + (size_t)64 * K;
    const unsigned short* Bg0 = B + (size_t)(col0 + t / 4) * K + (t % 4) * 8;
    const unsigned short* Bg1 = Bg0 + (size_t)64 * K;

    for (int k0 = 0; k0 < K; k0 += 32) {
        gload_lds16(Ag0 + k0, &As[t * 8]);
        gload_lds16(Ag1 + k0, &As[2048 + t * 8]);
        gload_lds16(Bg0 + k0, &Bs[t * 8]);
        gload_lds16(Bg1 + k0, &Bs[2048 + t * 8]);
        __syncthreads();
        bf16x8 af[4], bfr[4];
#pragma unroll
        for (int m = 0; m < 4; ++m)
            af[m] = *reinterpret_cast<const bf16x8*>(&As[(wr * 64 + m * 16 + lr) * 32 + lk]);
#pragma unroll
        for (int n = 0; n < 4; ++n)
            bfr[n] = *reinterpret_cast<const bf16x8*>(&Bs[(wc * 64 + n * 16 + lr) * 32 + lk]);
#pragma unroll
        for (int m = 0; m < 4; ++m)
#pragma unroll
            for (int n = 0; n < 4; ++n)
                acc[m][n] = __builtin_amdgcn_mfma_f32_16x16x32_bf16(af[m], bfr[n], acc[m][n], 0, 0, 0);
        __syncthreads();
    }

#pragma unroll
    for (int m = 0; m < 4; ++m) {
        int row_b = row0 + wr * 64 + m * 16 + (l >> 4) * 4;
#pragma unroll
        for (int n = 0; n < 4; ++n) {
            int col = col0 + wc * 64 + n * 16 + lr;
#pragma unroll
            for (int jr = 0; jr < 4; ++jr) {
                int row = row_b + jr;
                if (OUT_BF16)
                    ((unsigned short*)Cv)[(size_t)row * N + col] = f2bf(acc[m][n][jr]);
                else
                    ((float*)Cv)[(size_t)row * N + col] = acc[m][n][jr];
            }
        }
    }
}

// ---------------- RMSNorm + RoPE (bf16 in -> bf16 out), one wave per 128-vector ----------------
__global__ void norm_rope(const unsigned short* __restrict__ in, unsigned short* __restrict__ out,
                          const float* __restrict__ sin_t, const float* __restrict__ cos_t,
                          const float* __restrict__ scale, const float* __restrict__ shift,
                          int nh) {
    int w = threadIdx.x >> 6, lane = threadIdx.x & 63;
    int vec = blockIdx.x * 4 + w;
    if (vec >= SEQ * nh) return;
    int s = vec / nh;
    const unsigned short* base = in + (size_t)vec * HD;
    float x1 = bf2f(base[lane]), x2 = bf2f(base[lane + 64]);
    float ss = x1 * x1 + x2 * x2;
#pragma unroll
    for (int off = 1; off < 64; off <<= 1) ss += __shfl_xor(ss, off, 64);
    float rinv = rsqrtf(ss * (1.0f / 128.0f) + 1e-6f);
    float xn1 = x1 * rinv * (1.0f + scale[lane]) + shift[lane];
    float xn2 = x2 * rinv * (1.0f + scale[lane + 64]) + shift[lane + 64];
    float c1 = cos_t[s * HD + lane], s1 = sin_t[s * HD + lane];
    float c2 = cos_t[s * HD + lane + 64], s2 = sin_t[s * HD + lane + 64];
    float o1 = xn1 * c1 - xn2 * s1;   // rot[d<64] = -x[d+64]
    float o2 = xn2 * c2 + xn1 * s2;   // rot[d>=64] = x[d-64]
    out[(size_t)vec * HD + lane] = f2bf(o1);
    out[(size_t)vec * HD + lane + 64] = f2bf(o2);
}

// ---------------- flash causal attention ----------------
// grid: (SEQ/64, NH); block 256 = 4 waves; wave w owns 16 q-rows.
__launch_bounds__(256)
__global__ void flash_attn(const unsigned short* __restrict__ Q,
                           const unsigned short* __restrict__ Kb,
                           const unsigned short* __restrict__ Vb,
                           unsigned short* __restrict__ O) {
    __shared__ __align__(16) unsigned short Ks[64 * 128];   // [key][d], XOR-swizzled
    __shared__ __align__(16) unsigned short Vt[128 * 64];   // [d][key], XOR-swizzled
    __shared__ __align__(16) unsigned short Pl[4][16 * 64]; // per-wave P, XOR-swizzled
    const int t = threadIdx.x, l = t & 63, w = t >> 6;
    const int h = blockIdx.y, qt = blockIdx.x;
    const int q0 = qt * 64;
    const int lr = l & 15, lk = (l >> 4) * 8;
    const float sc = 0.08838834764831845f; // 1/sqrt(128)

    bf16x8 qf[4];
    const unsigned short* qbase = Q + (size_t)(q0 + w * 16 + lr) * (NH * HD) + h * HD + lk;
#pragma unroll
    for (int kf = 0; kf < 4; ++kf)
        qf[kf] = *reinterpret_cast<const bf16x8*>(qbase + kf * 32);

    f32x4 acc[8] = {};
    float mrow[4] = {-1e30f, -1e30f, -1e30f, -1e30f};
    float lrow[4] = {0.f, 0.f, 0.f, 0.f};

    for (int kt = 0; kt <= qt; ++kt) {
        const int k0 = kt * 64;
        // stage K tile [64][128] with elem-swizzle col ^= (row&7)<<3
#pragma unroll
        for (int i = 0; i < 4; ++i) {
            int chunk = t + i * 256;
            int row = chunk >> 4, c0 = (chunk & 15) * 8;
            bf16x8 v = *reinterpret_cast<const bf16x8*>(Kb + (size_t)(k0 + row) * HD + c0);
            *reinterpret_cast<bf16x8*>(&Ks[row * 128 + (c0 ^ ((row & 7) << 3))]) = v;
        }
        // stage V transposed: Vt[d][k], swizzle k ^= (d&7)<<3
#pragma unroll
        for (int i = 0; i < 4; ++i) {
            int chunk = t + i * 256;
            int kk = chunk >> 4, d0 = (chunk & 15) * 8;
            bf16x8 v = *reinterpret_cast<const bf16x8*>(Vb + (size_t)(k0 + kk) * HD + d0);
#pragma unroll
            for (int j = 0; j < 8; ++j) {
                int d = d0 + j;
                Vt[d * 64 + (kk ^ ((d & 7) << 3))] = (unsigned short)v[j];
            }
        }
        __syncthreads();

        // S = Q * K^T  (16 x 64 per wave)
        f32x4 s4[4];
#pragma unroll
        for (int nf = 0; nf < 4; ++nf) {
            f32x4 a = {};
#pragma unroll
            for (int kf = 0; kf < 4; ++kf) {
                int row = nf * 16 + lr;
                bf16x8 kfrag = *reinterpret_cast<const bf16x8*>(
                    &Ks[row * 128 + ((kf * 32 + lk) ^ ((row & 7) << 3))]);
                a = __builtin_amdgcn_mfma_f32_16x16x32_bf16(qf[kf], kfrag, a, 0, 0, 0);
            }
            s4[nf] = a;
        }

        // online softmax per row (4 rows/lane, replicated over 16 lanes)
#pragma unroll
        for (int jr = 0; jr < 4; ++jr) {
            int qrow = q0 + w * 16 + (l >> 4) * 4 + jr;
            float sv[4];
#pragma unroll
            for (int nf = 0; nf < 4; ++nf) {
                int kcol = k0 + nf * 16 + lr;
                float x = s4[nf][jr] * sc;
                sv[nf] = (kcol > qrow) ? -1e30f : x;
            }
            float mx = fmaxf(fmaxf(sv[0], sv[1]), fmaxf(sv[2], sv[3]));
            mx = fmaxf(mx, __shfl_xor(mx, 1, 64));
            mx = fmaxf(mx, __shfl_xor(mx, 2, 64));
            mx = fmaxf(mx, __shfl_xor(mx, 4, 64));
            mx = fmaxf(mx, __shfl_xor(mx, 8, 64));
            float mnew = fmaxf(mrow[jr], mx);
            float corr = __expf(mrow[jr] - mnew);
            float ps = 0.f;
            int row = (l >> 4) * 4 + jr;
#pragma unroll
            for (int nf = 0; nf < 4; ++nf) {
                float p = __expf(sv[nf] - mnew);
                ps += p;
                int col = nf * 16 + lr;
                Pl[w][row * 64 + (col ^ ((row & 7) << 3))] = f2bf(p);
            }
            ps += __shfl_xor(ps, 1, 64);
            ps += __shfl_xor(ps, 2, 64);
            ps += __shfl_xor(ps, 4, 64);
            ps += __shfl_xor(ps, 8, 64);
            lrow[jr] = lrow[jr] * corr + ps;
            mrow[jr] = mnew;
#pragma unroll
            for (int nf = 0; nf < 8; ++nf) acc[nf][jr] *= corr;
        }

        // O += P * V
#pragma unroll
        for (int kf = 0; kf < 2; ++kf) {
            bf16x8 pf = *reinterpret_cast<const bf16x8*>(
                &Pl[w][lr * 64 + ((kf * 32 + lk) ^ ((lr & 7) << 3))]);
#pragma unroll
            for (int nf = 0; nf < 8; ++nf) {
                int n = nf * 16 + lr;
                bf16x8 vf = *reinterpret_cast<const bf16x8*>(
                    &Vt[n * 64 + ((kf * 32 + lk) ^ ((n & 7) << 3))]);
                acc[nf] = __builtin_amdgcn_mfma_f32_16x16x32_bf16(pf, vf, acc[nf], 0, 0, 0);
            }
        }
        __syncthreads();
    }

#pragma unroll
    for (int jr = 0; jr < 4; ++jr) {
        float inv = 1.0f / lrow[jr];
        int row = q0 + w * 16 + (l >> 4) * 4 + jr;
#pragma unroll
        for (int nf = 0; nf < 8; ++nf) {
            int col = nf * 16 + lr;
            O[(size_t)row * (NH * HD) + h * HD + col] = f2bf(acc[nf][jr] * inv);
        }
    }
}

extern "C" void kernel_launch(void* const* d_in, const int* in_sizes, int n_in,
                              void* d_out, int out_size, void* d_ws, size_t ws_size,
                              hipStream_t stream) {
    const float* x      = (const float*)d_in[0];
    // d_in[1] = mask (unused; causal triu(k=1) is hard-coded)
    const float* sin_t  = (const float*)d_in[2];
    const float* cos_t  = (const float*)d_in[3];
    const float* w_q    = (const float*)d_in[4];
    const float* w_k    = (const float*)d_in[5];
    const float* w_v    = (const float*)d_in[6];
    const float* w_o    = (const float*)d_in[7];
    const float* q_scale = (const float*)d_in[8];
    const float* q_shift = (const float*)d_in[9];
    const float* k_scale = (const float*)d_in[10];
    const float* k_shift = (const float*)d_in[11];
    float* out = (float*)d_out;

    char* ws = (char*)d_ws;
    const size_t MB = 1u << 20;
    unsigned short* xb   = (unsigned short*)(ws);                    // 8 MB  x bf16
    unsigned short* wqb  = (unsigned short*)(ws + 8 * MB);           // 8 MB
    unsigned short* wob  = (unsigned short*)(ws + 16 * MB);          // 8 MB
    unsigned short* wkb  = (unsigned short*)(ws + 24 * MB);          // 0.5 MB
    unsigned short* wvb  = (unsigned short*)(ws + 24 * MB + 512 * 1024); // 0.5 MB
    unsigned short* qpre = (unsigned short*)(ws + 25 * MB);          // 8 MB  pre-norm Q
    unsigned short* kpre = (unsigned short*)(ws + 33 * MB);          // 0.5 MB pre-norm K
    unsigned short* vb   = (unsigned short*)(ws + 33 * MB + 512 * 1024); // 0.5 MB
    unsigned short* qb   = (unsigned short*)(ws + 34 * MB);          // 8 MB  post-rope Q
    unsigned short* kb   = (unsigned short*)(ws + 42 * MB);          // 0.5 MB post-rope K
    unsigned short* ab   = (unsigned short*)(ws + 42 * MB + 512 * 1024); // 8 MB attn out
    // total ~50.5 MB

    auto cast = [&](const float* src, unsigned short* dst, int n) {
        cast_f32_bf16<<<(n / 4 + 255) / 256, 256, 0, stream>>>(src, dst, n);
    };
    cast(x,   xb,  SEQ * DIN);
    cast(w_q, wqb, NH * HD * DIN);
    cast(w_k, wkb, HD * DIN);
    cast(w_v, wvb, HD * DIN);
    cast(w_o, wob, DIN * NH * HD);

    // projections (bf16 out)
    gemm_bt<1><<<dim3(16, 16), 256, 0, stream>>>(xb, wqb, qpre, SEQ, NH * HD, DIN);
    gemm_bt<1><<<dim3(1, 16), 256, 0, stream>>>(xb, wkb, kpre, SEQ, HD, DIN);
    gemm_bt<1><<<dim3(1, 16), 256, 0, stream>>>(xb, wvb, vb, SEQ, HD, DIN);

    // norm + rope
    norm_rope<<<SEQ * NH / 4, 256, 0, stream>>>(qpre, qb, sin_t, cos_t, q_scale, q_shift, NH);
    norm_rope<<<SEQ / 4, 256, 0, stream>>>(kpre, kb, sin_t, cos_t, k_scale, k_shift, 1);

    // attention
    flash_attn<<<dim3(SEQ / 64, NH), 256, 0, stream>>>(qb, kb, vb, ab);

    // output projection (f32 out -> d_out)
    gemm_bt<0><<<dim3(16, 16), 256, 0, stream>>>(ab, wob, out, SEQ, NH * HD, DIN);
}

// Round 3
// 351.725 us; speedup vs baseline: 1.4248x; 1.4248x over previous
//
#include <hip/hip_runtime.h>
#include <stdint.h>

#define SEQ 2048
#define DIN 2048
#define NH 16
#define HD 128

typedef __attribute__((ext_vector_type(8))) short bf16x8;
typedef __attribute__((ext_vector_type(4))) float f32x4;

__device__ __forceinline__ unsigned short f2bf(float f) {
    unsigned int u = __float_as_uint(f);
    u += 0x7fff + ((u >> 16) & 1);   // round-to-nearest-even
    return (unsigned short)(u >> 16);
}

__device__ __forceinline__ float bf2f(unsigned short u) {
    return __uint_as_float(((unsigned int)u) << 16);
}

__device__ __forceinline__ void gload_lds16(const void* g, void* l) {
    __builtin_amdgcn_global_load_lds(
        (const __attribute__((address_space(1))) unsigned int*)g,
        (__attribute__((address_space(3))) unsigned int*)l,
        16, 0, 0);
}

// ---------------- cast f32 -> bf16 ----------------
__global__ void cast_f32_bf16(const float* __restrict__ in, unsigned short* __restrict__ out, int n) {
    int i = (blockIdx.x * blockDim.x + threadIdx.x) * 4;
    if (i >= n) return;
    float4 v = *reinterpret_cast<const float4*>(in + i);
    ushort4 o;
    o.x = f2bf(v.x); o.y = f2bf(v.y); o.z = f2bf(v.z); o.w = f2bf(v.w);
    *reinterpret_cast<ushort4*>(out + i) = o;
}

// ------- GEMM: C[M][N] = A[M][K] * B[N][K]^T. OUT_MODE: 0=f32, 1=bf16, 2=bf16 transposed (C^T[N][M]) -------
template<int OUT_MODE>
__launch_bounds__(256)
__global__ void gemm_bt(const unsigned short* __restrict__ A,
                        const unsigned short* __restrict__ B,
                        void* __restrict__ Cv, int M, int N, int K) {
    __shared__ __align__(16) unsigned short As[128 * 32];
    __shared__ __align__(16) unsigned short Bs[128 * 32];
    const int t = threadIdx.x;
    const int l = t & 63;
    const int w = t >> 6;
    const int wr = w >> 1, wc = w & 1;
    const int row0 = blockIdx.y * 128, col0 = blockIdx.x * 128;
    const int lr = l & 15, lk = (l >> 4) * 8;

    f32x4 acc[4][4] = {};

    const unsigned short* Ag0 = A + (size_t)(row0 + t / 4) * K + (t % 4) * 8;
    const unsigned short* Ag1 = Ag0 + (size_t)64 * K;
    const unsigned short* Bg0 = B + (size_t)(col0 + t / 4) * K + (t % 4) * 8;
    const unsigned short* Bg1 = Bg0 + (size_t)64 * K;

    for (int k0 = 0; k0 < K; k0 += 32) {
        gload_lds16(Ag0 + k0, &As[t * 8]);
        gload_lds16(Ag1 + k0, &As[2048 + t * 8]);
        gload_lds16(Bg0 + k0, &Bs[t * 8]);
        gload_lds16(Bg1 + k0, &Bs[2048 + t * 8]);
        __syncthreads();
        bf16x8 af[4], bfr[4];
#pragma unroll
        for (int m = 0; m < 4; ++m)
            af[m] = *reinterpret_cast<const bf16x8*>(&As[(wr * 64 + m * 16 + lr) * 32 + lk]);
#pragma unroll
        for (int n = 0; n < 4; ++n)
            bfr[n] = *reinterpret_cast<const bf16x8*>(&Bs[(wc * 64 + n * 16 + lr) * 32 + lk]);
#pragma unroll
        for (int m = 0; m < 4; ++m)
#pragma unroll
            for (int n = 0; n < 4; ++n)
                acc[m][n] = __builtin_amdgcn_mfma_f32_16x16x32_bf16(af[m], bfr[n], acc[m][n], 0, 0, 0);
        __syncthreads();
    }

#pragma unroll
    for (int m = 0; m < 4; ++m) {
        int row_b = row0 + wr * 64 + m * 16 + (l >> 4) * 4;
#pragma unroll
        for (int n = 0; n < 4; ++n) {
            int col = col0 + wc * 64 + n * 16 + lr;
#pragma unroll
            for (int jr = 0; jr < 4; ++jr) {
                int row = row_b + jr;
                if (OUT_MODE == 0)
                    ((float*)Cv)[(size_t)row * N + col] = acc[m][n][jr];
                else if (OUT_MODE == 1)
                    ((unsigned short*)Cv)[(size_t)row * N + col] = f2bf(acc[m][n][jr]);
                else
                    ((unsigned short*)Cv)[(size_t)col * M + row] = f2bf(acc[m][n][jr]);
            }
        }
    }
}

// ---------------- RMSNorm + RoPE (bf16 in -> bf16 out), one wave per 128-vector ----------------
__global__ void norm_rope(const unsigned short* __restrict__ in, int srow,
                          unsigned short* __restrict__ out,
                          const float* __restrict__ sin_t, const float* __restrict__ cos_t,
                          const float* __restrict__ scale, const float* __restrict__ shift,
                          int nh) {
    int w = threadIdx.x >> 6, lane = threadIdx.x & 63;
    int vec = blockIdx.x * 4 + w;
    if (vec >= SEQ * nh) return;
    int s = vec / nh, hh = vec % nh;
    const unsigned short* base = in + (size_t)s * srow + hh * HD;
    float x1 = bf2f(base[lane]), x2 = bf2f(base[lane + 64]);
    float ss = x1 * x1 + x2 * x2;
#pragma unroll
    for (int off = 1; off < 64; off <<= 1) ss += __shfl_xor(ss, off, 64);
    float rinv = rsqrtf(ss * (1.0f / 128.0f) + 1e-6f);
    float xn1 = x1 * rinv * (1.0f + scale[lane]) + shift[lane];
    float xn2 = x2 * rinv * (1.0f + scale[lane + 64]) + shift[lane + 64];
    float c1 = cos_t[s * HD + lane], s1 = sin_t[s * HD + lane];
    float c2 = cos_t[s * HD + lane + 64], s2 = sin_t[s * HD + lane + 64];
    float o1 = xn1 * c1 - xn2 * s1;
    float o2 = xn2 * c2 + xn1 * s2;
    out[(size_t)vec * HD + lane] = f2bf(o1);
    out[(size_t)vec * HD + lane + 64] = f2bf(o2);
}

// ---------------- flash causal attention v2 ----------------
// grid (16 pairs, 16 heads) = 256 blocks; block = 4 waves; wave owns 16 q-rows of a 64-row tile.
// Block processes q-tiles {p, 31-p} sequentially -> 33 K-tile iters per block, balanced.
// K and V^T staged via global_load_lds with pre-swizzled global source (XOR involution).
__launch_bounds__(256)
__global__ void flash_attn2(const unsigned short* __restrict__ Q,
                            const unsigned short* __restrict__ Kb,
                            const unsigned short* __restrict__ Vtg,  // [HD][SEQ]
                            unsigned short* __restrict__ O) {
    __shared__ __align__(16) unsigned short Ks[2][64 * 128];
    __shared__ __align__(16) unsigned short Vs[2][128 * 64];
    __shared__ __align__(16) unsigned short Pl[4][16 * 64];
    const int t = threadIdx.x, l = t & 63, w = t >> 6;
    const int h = blockIdx.y;
    const int lr = l & 15, g = l >> 4, lk = g * 8;
    const float sc = 0.08838834764831845f; // 1/sqrt(128)

    auto stage = [&](int buf, int k0) {
#pragma unroll
        for (int i = 0; i < 4; ++i) {
            int c = w * 256 + i * 64 + l;
            int kr = c >> 4, kc = c & 15;
            gload_lds16(Kb + (size_t)(k0 + kr) * HD + ((kc ^ (kr & 7)) * 8),
                        &Ks[buf][c * 8]);
            int vd = c >> 3, vc = c & 7;
            gload_lds16(Vtg + (size_t)vd * SEQ + k0 + ((vc ^ (vd & 7)) * 8),
                        &Vs[buf][c * 8]);
        }
    };

    auto process = [&](int qt) {
        const int q0 = qt * 64;
        bf16x8 qf[4];
        const unsigned short* qbase = Q + (size_t)(q0 + w * 16 + lr) * (NH * HD) + h * HD + lk;
#pragma unroll
        for (int kf = 0; kf < 4; ++kf)
            qf[kf] = *reinterpret_cast<const bf16x8*>(qbase + kf * 32);

        f32x4 acc[8] = {};
        float mrow[4] = {-1e30f, -1e30f, -1e30f, -1e30f};
        float lrow[4] = {0.f, 0.f, 0.f, 0.f};
        const int nt = qt + 1;
        int buf = 0;
        stage(0, 0);
        __syncthreads();

        for (int kt = 0; kt < nt; ++kt) {
            if (kt + 1 < nt) stage(buf ^ 1, (kt + 1) * 64);

            // S = Q K^T (16 q-rows x 64 keys per wave)
            f32x4 s4[4];
#pragma unroll
            for (int nf = 0; nf < 4; ++nf) {
                int row = nf * 16 + lr;
                f32x4 a = {};
#pragma unroll
                for (int kf = 0; kf < 4; ++kf) {
                    bf16x8 kfrag = *reinterpret_cast<const bf16x8*>(
                        &Ks[buf][row * 128 + ((kf * 32 + lk) ^ ((row & 7) << 3))]);
                    a = __builtin_amdgcn_mfma_f32_16x16x32_bf16(qf[kf], kfrag, a, 0, 0, 0);
                }
                s4[nf] = a;
            }

            // scale + (diagonal-only) mask
            float sv[4][4];
            const bool diag = (kt == qt);
#pragma unroll
            for (int jr = 0; jr < 4; ++jr)
#pragma unroll
                for (int nf = 0; nf < 4; ++nf) {
                    float x = s4[nf][jr] * sc;
                    if (diag && (nf * 16 + lr > w * 16 + g * 4 + jr)) x = -1e30f;
                    sv[jr][nf] = x;
                }

            // per-row max (across the 16 lanes holding the row's columns)
            float mx[4];
#pragma unroll
            for (int jr = 0; jr < 4; ++jr) {
                float m2 = fmaxf(fmaxf(sv[jr][0], sv[jr][1]), fmaxf(sv[jr][2], sv[jr][3]));
                m2 = fmaxf(m2, __shfl_xor(m2, 1, 64));
                m2 = fmaxf(m2, __shfl_xor(m2, 2, 64));
                m2 = fmaxf(m2, __shfl_xor(m2, 4, 64));
                m2 = fmaxf(m2, __shfl_xor(m2, 8, 64));
                mx[jr] = m2;
            }
            int pred = (mx[0] - mrow[0] <= 8.f) && (mx[1] - mrow[1] <= 8.f) &&
                       (mx[2] - mrow[2] <= 8.f) && (mx[3] - mrow[3] <= 8.f);
            const bool skip = __all(pred);   // defer-max (T13)

#pragma unroll
            for (int jr = 0; jr < 4; ++jr) {
                float mnew = skip ? mrow[jr] : fmaxf(mrow[jr], mx[jr]);
                int row = g * 4 + jr;
                float ps = 0.f;
#pragma unroll
                for (int nf = 0; nf < 4; ++nf) {
                    float p = __expf(sv[jr][nf] - mnew);
                    ps += p;
                    int col = nf * 16 + lr;
                    Pl[w][row * 64 + (col ^ ((row & 12) << 2))] = f2bf(p);
                }
                ps += __shfl_xor(ps, 1, 64);
                ps += __shfl_xor(ps, 2, 64);
                ps += __shfl_xor(ps, 4, 64);
                ps += __shfl_xor(ps, 8, 64);
                if (!skip) {
                    float corr = __expf(mrow[jr] - mnew);
                    mrow[jr] = mnew;
                    lrow[jr] = lrow[jr] * corr + ps;
#pragma unroll
                    for (int nf = 0; nf < 8; ++nf) acc[nf][jr] *= corr;
                } else {
                    lrow[jr] += ps;
                }
            }

            asm volatile("s_waitcnt lgkmcnt(0)" ::: "memory");
            __builtin_amdgcn_sched_barrier(0);

            // O += P V
#pragma unroll
            for (int kf = 0; kf < 2; ++kf) {
                bf16x8 pf = *reinterpret_cast<const bf16x8*>(
                    &Pl[w][lr * 64 + ((kf * 32 + lk) ^ ((lr & 12) << 2))]);
#pragma unroll
                for (int nf = 0; nf < 8; ++nf) {
                    int d = nf * 16 + lr;
                    bf16x8 vf = *reinterpret_cast<const bf16x8*>(
                        &Vs[buf][d * 64 + ((kf * 32 + lk) ^ ((d & 7) << 3))]);
                    acc[nf] = __builtin_amdgcn_mfma_f32_16x16x32_bf16(pf, vf, acc[nf], 0, 0, 0);
                }
            }
            __syncthreads();
            buf ^= 1;
        }

#pragma unroll
        for (int jr = 0; jr < 4; ++jr) {
            float inv = 1.0f / lrow[jr];
            int row = q0 + w * 16 + g * 4 + jr;
#pragma unroll
            for (int nf = 0; nf < 8; ++nf) {
                int col = nf * 16 + lr;
                O[(size_t)row * (NH * HD) + h * HD + col] = f2bf(acc[nf][jr] * inv);
            }
        }
    };

    process(blockIdx.x);
    process(31 - blockIdx.x);
}

extern "C" void kernel_launch(void* const* d_in, const int* in_sizes, int n_in,
                              void* d_out, int out_size, void* d_ws, size_t ws_size,
                              hipStream_t stream) {
    const float* x      = (const float*)d_in[0];
    const float* sin_t  = (const float*)d_in[2];
    const float* cos_t  = (const float*)d_in[3];
    const float* w_q    = (const float*)d_in[4];
    const float* w_k    = (const float*)d_in[5];
    const float* w_v    = (const float*)d_in[6];
    const float* w_o    = (const float*)d_in[7];
    const float* q_scale = (const float*)d_in[8];
    const float* q_shift = (const float*)d_in[9];
    const float* k_scale = (const float*)d_in[10];
    const float* k_shift = (const float*)d_in[11];
    float* out = (float*)d_out;

    char* ws = (char*)d_ws;
    const size_t MB = 1u << 20;
    unsigned short* xb    = (unsigned short*)(ws);                        // 8 MB   x bf16 [2048][2048]
    unsigned short* wqkb  = (unsigned short*)(ws + 8 * MB);               // 8.5 MB w_q|w_k [2176][2048]
    unsigned short* wvb   = (unsigned short*)(ws + 16 * MB + 512 * 1024); // 0.5 MB w_v [128][2048]
    unsigned short* wob   = (unsigned short*)(ws + 17 * MB);              // 8 MB   w_o [2048][2048]
    unsigned short* qkpre = (unsigned short*)(ws + 25 * MB);              // 8.5 MB pre-norm Q|K [2048][2176]
    unsigned short* vtb   = (unsigned short*)(ws + 33 * MB + 512 * 1024); // 0.5 MB V^T [128][2048]
    unsigned short* qb    = (unsigned short*)(ws + 34 * MB);              // 8 MB   post-rope Q
    unsigned short* kb    = (unsigned short*)(ws + 42 * MB);              // 0.5 MB post-rope K
    unsigned short* ab    = (unsigned short*)(ws + 42 * MB + 512 * 1024); // 8 MB   attn out
    // total ~50.5 MB

    auto cast = [&](const float* src, unsigned short* dst, int n) {
        cast_f32_bf16<<<(n / 4 + 255) / 256, 256, 0, stream>>>(src, dst, n);
    };
    cast(x,   xb,   SEQ * DIN);
    cast(w_q, wqkb, NH * HD * DIN);
    cast(w_k, wqkb + (size_t)NH * HD * DIN, HD * DIN);
    cast(w_v, wvb,  HD * DIN);
    cast(w_o, wob,  DIN * NH * HD);

    // fused Q|K projection (N = 2176) and V projection (transposed output)
    gemm_bt<1><<<dim3(17, 16), 256, 0, stream>>>(xb, wqkb, qkpre, SEQ, NH * HD + HD, DIN);
    gemm_bt<2><<<dim3(1, 16), 256, 0, stream>>>(xb, wvb, vtb, SEQ, HD, DIN);

    // norm + rope
    norm_rope<<<SEQ * NH / 4, 256, 0, stream>>>(qkpre, NH * HD + HD, qb, sin_t, cos_t, q_scale, q_shift, NH);
    norm_rope<<<SEQ / 4, 256, 0, stream>>>(qkpre + NH * HD, NH * HD + HD, kb, sin_t, cos_t, k_scale, k_shift, 1);

    // attention
    flash_attn2<<<dim3(16, 16), 256, 0, stream>>>(qb, kb, vtb, ab);

    // output projection (f32 out -> d_out)
    gemm_bt<0><<<dim3(16, 16), 256, 0, stream>>>(ab, wob, out, SEQ, NH * HD, DIN);
}